// Round 2
// baseline (298.711 us; speedup 1.0000x reference)
//
#include <hip/hip_runtime.h>
#include <hip/hip_bf16.h>

#define D_IN   2048
#define D_ST   16
#define DT_RK  64
#define BB     2
#define LL     2048
#define NCHUNK 64
#define LC     (LL / NCHUNK)   // 32
#define LOG2E  1.4426950408889634f

// ---------------------------------------------------------------------------
// Kernel 1: x_dbl[bl][k] = sum_d u[bl][d] * W_x[k][d]   (M=4096, N=96, K=2048)
// Split-K (8 ways) with fp32 atomicAdd epilogue. Block: 64 rows x 96 cols.
// ---------------------------------------------------------------------------
#define G1_MT 64
#define G1_KSPLIT 8
#define G1_KPER (D_IN / G1_KSPLIT)  // 256
#define G1_KC 64

__global__ __launch_bounds__(256) void gemm_xdbl(const float* __restrict__ u,
                                                 const float* __restrict__ Wx,
                                                 float* __restrict__ xdbl) {
    __shared__ float us[G1_MT][G1_KC + 4];   // +4 pad: kill 64-stride bank conflicts
    __shared__ float wxs[96][G1_KC + 4];
    const int mt  = blockIdx.x / G1_KSPLIT;
    const int ks  = blockIdx.x % G1_KSPLIT;
    const int row0 = mt * G1_MT;
    const int kb0  = ks * G1_KPER;
    const int tid = threadIdx.x;
    const int r0 = (tid & 15) * 4;   // 4 rows
    const int c0 = (tid >> 4) * 6;   // 6 cols

    float acc[4][6];
#pragma unroll
    for (int i = 0; i < 4; i++)
#pragma unroll
        for (int j = 0; j < 6; j++) acc[i][j] = 0.f;

    for (int kc = 0; kc < G1_KPER; kc += G1_KC) {
        const int kb = kb0 + kc;
        // stage u tile: 64 rows x 64 k  (1024 float4, 4 per thread)
#pragma unroll
        for (int i = 0; i < 4; i++) {
            int f4 = tid + i * 256;
            int r = f4 >> 4, k4 = (f4 & 15) * 4;
            *(float4*)&us[r][k4] =
                *(const float4*)&u[(size_t)(row0 + r) * D_IN + kb + k4];
        }
        // stage Wx tile: 96 x 64  (1536 float4, 6 per thread)
#pragma unroll
        for (int i = 0; i < 6; i++) {
            int f4 = tid + i * 256;
            int c = f4 >> 4, k4 = (f4 & 15) * 4;
            *(float4*)&wxs[c][k4] =
                *(const float4*)&Wx[(size_t)c * D_IN + kb + k4];
        }
        __syncthreads();
#pragma unroll 4
        for (int k4 = 0; k4 < G1_KC; k4 += 4) {
            float4 av[4], bv[6];
#pragma unroll
            for (int i = 0; i < 4; i++) av[i] = *(const float4*)&us[r0 + i][k4];
#pragma unroll
            for (int j = 0; j < 6; j++) bv[j] = *(const float4*)&wxs[c0 + j][k4];
#pragma unroll
            for (int i = 0; i < 4; i++)
#pragma unroll
                for (int j = 0; j < 6; j++) {
                    acc[i][j] = fmaf(av[i].x, bv[j].x, acc[i][j]);
                    acc[i][j] = fmaf(av[i].y, bv[j].y, acc[i][j]);
                    acc[i][j] = fmaf(av[i].z, bv[j].z, acc[i][j]);
                    acc[i][j] = fmaf(av[i].w, bv[j].w, acc[i][j]);
                }
        }
        __syncthreads();
    }
#pragma unroll
    for (int i = 0; i < 4; i++)
#pragma unroll
        for (int j = 0; j < 6; j++)
            atomicAdd(&xdbl[(size_t)(row0 + r0 + i) * 96 + c0 + j], acc[i][j]);
}

// ---------------------------------------------------------------------------
// Kernel 2: dt[bl][d] = softplus( sum_r xdbl[bl][r] * W_dt[d][r] + b_dt[d] )
// M=4096, N=2048, K=64. Block: 32 rows x 128 cols, K in full.
// ---------------------------------------------------------------------------
#define G2_MT 32
#define G2_NT 128

__global__ __launch_bounds__(256) void gemm_dt(const float* __restrict__ xdbl,
                                               const float* __restrict__ Wdt,
                                               const float* __restrict__ bdt,
                                               float* __restrict__ dt) {
    __shared__ float rs[G2_MT][DT_RK + 4];
    __shared__ float wds[G2_NT][DT_RK + 4];
    const int rt = blockIdx.x >> 4;    // 128 row tiles
    const int ct = blockIdx.x & 15;    // 16 col tiles
    const int row0 = rt * G2_MT, col0 = ct * G2_NT;
    const int tid = threadIdx.x;

#pragma unroll
    for (int i = 0; i < 2; i++) {
        int f4 = tid + i * 256;        // 0..511
        int r = f4 >> 4, k4 = (f4 & 15) * 4;
        *(float4*)&rs[r][k4] = *(const float4*)&xdbl[(size_t)(row0 + r) * 96 + k4];
    }
#pragma unroll
    for (int i = 0; i < 8; i++) {
        int f4 = tid + i * 256;        // 0..2047
        int c = f4 >> 4, k4 = (f4 & 15) * 4;
        *(float4*)&wds[c][k4] = *(const float4*)&Wdt[(size_t)(col0 + c) * DT_RK + k4];
    }
    __syncthreads();

    const int r0 = (tid & 7) * 4;      // 4 rows
    const int c0 = (tid >> 3) * 4;     // 4 cols
    float acc[4][4];
#pragma unroll
    for (int i = 0; i < 4; i++)
#pragma unroll
        for (int j = 0; j < 4; j++) acc[i][j] = 0.f;

#pragma unroll
    for (int k4 = 0; k4 < DT_RK; k4 += 4) {
        float4 av[4], bv[4];
#pragma unroll
        for (int i = 0; i < 4; i++) av[i] = *(const float4*)&rs[r0 + i][k4];
#pragma unroll
        for (int j = 0; j < 4; j++) bv[j] = *(const float4*)&wds[c0 + j][k4];
#pragma unroll
        for (int i = 0; i < 4; i++)
#pragma unroll
            for (int j = 0; j < 4; j++) {
                acc[i][j] = fmaf(av[i].x, bv[j].x, acc[i][j]);
                acc[i][j] = fmaf(av[i].y, bv[j].y, acc[i][j]);
                acc[i][j] = fmaf(av[i].z, bv[j].z, acc[i][j]);
                acc[i][j] = fmaf(av[i].w, bv[j].w, acc[i][j]);
            }
    }
#pragma unroll
    for (int j = 0; j < 4; j++) {
        float bj = bdt[col0 + c0 + j];
#pragma unroll
        for (int i = 0; i < 4; i++) {
            float x = acc[i][j] + bj;
            // softplus, overflow-safe
            float sp = fmaxf(x, 0.f) + log1pf(expf(-fabsf(x)));
            dt[(size_t)(row0 + r0 + i) * D_IN + col0 + c0 + j] = sp;
        }
    }
}

// ---------------------------------------------------------------------------
// Scan pass 1: per (b, chunk, d): local scan from h=0 over LC steps.
// Outputs: Ssum[b][c][d] = sum dt;  q[b][c][n][d] = local final state.
// ---------------------------------------------------------------------------
__global__ __launch_bounds__(256) void scan_pass1(const float* __restrict__ u,
                                                  const float* __restrict__ dt,
                                                  const float* __restrict__ xdbl,
                                                  const float* __restrict__ Alog,
                                                  float* __restrict__ Ssum,
                                                  float* __restrict__ q) {
    __shared__ float bc[LC][32];   // [t][0:16]=B_t, [t][16:32]=C_t
    const int blk = blockIdx.x;
    const int b  = blk >> 9;          // / (64 chunks * 8 dblocks)
    const int c  = (blk >> 3) & 63;
    const int db = blk & 7;
    const int tid = threadIdx.x;
    const int d = db * 256 + tid;
    const int t0 = c * LC;

    {   // stage B/C rows: LC*32 = 1024 floats = 256 float4
        int t = tid >> 3, j4 = (tid & 7) * 4;
        *(float4*)&bc[t][j4] =
            *(const float4*)&xdbl[(size_t)(b * LL + t0 + t) * 96 + 64 + j4];
    }
    float A2[16];
#pragma unroll
    for (int n4 = 0; n4 < 4; n4++) {
        float4 a = *(const float4*)&Alog[(size_t)d * 16 + n4 * 4];
        A2[n4 * 4 + 0] = -expf(a.x) * LOG2E;
        A2[n4 * 4 + 1] = -expf(a.y) * LOG2E;
        A2[n4 * 4 + 2] = -expf(a.z) * LOG2E;
        A2[n4 * 4 + 3] = -expf(a.w) * LOG2E;
    }
    __syncthreads();

    float h[16];
#pragma unroll
    for (int n = 0; n < 16; n++) h[n] = 0.f;
    float S = 0.f;

    const float* dtp = &dt[(size_t)(b * LL + t0) * D_IN + d];
    const float* up  = &u [(size_t)(b * LL + t0) * D_IN + d];
    float dt_nxt = dtp[0], u_nxt = up[0];
    for (int t = 0; t < LC; t++) {
        float dv = dt_nxt, uv = u_nxt;
        if (t + 1 < LC) { dt_nxt = dtp[(size_t)(t + 1) * D_IN]; u_nxt = up[(size_t)(t + 1) * D_IN]; }
        S += dv;
        float dtu = dv * uv;
        float4 b0 = *(const float4*)&bc[t][0];
        float4 b1 = *(const float4*)&bc[t][4];
        float4 b2 = *(const float4*)&bc[t][8];
        float4 b3 = *(const float4*)&bc[t][12];
        const float Bt[16] = {b0.x,b0.y,b0.z,b0.w, b1.x,b1.y,b1.z,b1.w,
                              b2.x,b2.y,b2.z,b2.w, b3.x,b3.y,b3.z,b3.w};
#pragma unroll
        for (int n = 0; n < 16; n++) {
            float a = __builtin_amdgcn_exp2f(dv * A2[n]);
            h[n] = fmaf(a, h[n], dtu * Bt[n]);
        }
    }
    Ssum[(size_t)(b * NCHUNK + c) * D_IN + d] = S;
#pragma unroll
    for (int n = 0; n < 16; n++)
        q[((size_t)((b * NCHUNK + c) * 16 + n)) * D_IN + d] = h[n];
}

// ---------------------------------------------------------------------------
// Combine: per (b,n,d): sequentially fold chunks IN-PLACE.
// On exit q[b][c][n][d] holds h_init for chunk c (the pre-chunk state).
// ---------------------------------------------------------------------------
__global__ __launch_bounds__(256) void scan_combine(const float* __restrict__ Alog,
                                                    const float* __restrict__ Ssum,
                                                    float* __restrict__ q) {
    const int gid = blockIdx.x * 256 + threadIdx.x;  // B*16*2048 = 65536
    const int d = gid & 2047;
    const int n = (gid >> 11) & 15;
    const int b = gid >> 15;
    const float A2 = -expf(Alog[(size_t)d * 16 + n]) * LOG2E;
    float h = 0.f;
    for (int c = 0; c < NCHUNK; c++) {
        size_t idx = ((size_t)((b * NCHUNK + c) * 16 + n)) * D_IN + d;
        float qv = q[idx];
        float S  = Ssum[(size_t)(b * NCHUNK + c) * D_IN + d];
        q[idx] = h;   // h_init for chunk c
        h = fmaf(__builtin_amdgcn_exp2f(A2 * S), h, qv);
    }
}

// ---------------------------------------------------------------------------
// Scan pass 2: re-scan each chunk from h_init, emit y = sum_n h*C + u*D (fp32)
// ---------------------------------------------------------------------------
__global__ __launch_bounds__(256) void scan_pass2(const float* __restrict__ u,
                                                  const float* __restrict__ dt,
                                                  const float* __restrict__ xdbl,
                                                  const float* __restrict__ Alog,
                                                  const float* __restrict__ Dv,
                                                  const float* __restrict__ hinit,
                                                  float* __restrict__ out) {
    __shared__ float bc[LC][32];
    const int blk = blockIdx.x;
    const int b  = blk >> 9;
    const int c  = (blk >> 3) & 63;
    const int db = blk & 7;
    const int tid = threadIdx.x;
    const int d = db * 256 + tid;
    const int t0 = c * LC;

    {
        int t = tid >> 3, j4 = (tid & 7) * 4;
        *(float4*)&bc[t][j4] =
            *(const float4*)&xdbl[(size_t)(b * LL + t0 + t) * 96 + 64 + j4];
    }
    float A2[16];
#pragma unroll
    for (int n4 = 0; n4 < 4; n4++) {
        float4 a = *(const float4*)&Alog[(size_t)d * 16 + n4 * 4];
        A2[n4 * 4 + 0] = -expf(a.x) * LOG2E;
        A2[n4 * 4 + 1] = -expf(a.y) * LOG2E;
        A2[n4 * 4 + 2] = -expf(a.z) * LOG2E;
        A2[n4 * 4 + 3] = -expf(a.w) * LOG2E;
    }
    const float Dd = Dv[d];
    float h[16];
#pragma unroll
    for (int n = 0; n < 16; n++)
        h[n] = hinit[((size_t)((b * NCHUNK + c) * 16 + n)) * D_IN + d];
    __syncthreads();

    const float* dtp = &dt[(size_t)(b * LL + t0) * D_IN + d];
    const float* up  = &u [(size_t)(b * LL + t0) * D_IN + d];
    float* op = &out[(size_t)(b * LL + t0) * D_IN + d];
    float dt_nxt = dtp[0], u_nxt = up[0];
    for (int t = 0; t < LC; t++) {
        float dv = dt_nxt, uv = u_nxt;
        if (t + 1 < LC) { dt_nxt = dtp[(size_t)(t + 1) * D_IN]; u_nxt = up[(size_t)(t + 1) * D_IN]; }
        float dtu = dv * uv;
        float4 b0 = *(const float4*)&bc[t][0];
        float4 b1 = *(const float4*)&bc[t][4];
        float4 b2 = *(const float4*)&bc[t][8];
        float4 b3 = *(const float4*)&bc[t][12];
        float4 c0v = *(const float4*)&bc[t][16];
        float4 c1v = *(const float4*)&bc[t][20];
        float4 c2v = *(const float4*)&bc[t][24];
        float4 c3v = *(const float4*)&bc[t][28];
        const float Bt[16] = {b0.x,b0.y,b0.z,b0.w, b1.x,b1.y,b1.z,b1.w,
                              b2.x,b2.y,b2.z,b2.w, b3.x,b3.y,b3.z,b3.w};
        const float Ct[16] = {c0v.x,c0v.y,c0v.z,c0v.w, c1v.x,c1v.y,c1v.z,c1v.w,
                              c2v.x,c2v.y,c2v.z,c2v.w, c3v.x,c3v.y,c3v.z,c3v.w};
        float y = 0.f;
#pragma unroll
        for (int n = 0; n < 16; n++) {
            float a = __builtin_amdgcn_exp2f(dv * A2[n]);
            h[n] = fmaf(a, h[n], dtu * Bt[n]);
            y = fmaf(h[n], Ct[n], y);
        }
        op[(size_t)t * D_IN] = fmaf(uv, Dd, y);
    }
}

// ---------------------------------------------------------------------------
extern "C" void kernel_launch(void* const* d_in, const int* in_sizes, int n_in,
                              void* d_out, int out_size, void* d_ws, size_t ws_size,
                              hipStream_t stream) {
    const float* u    = (const float*)d_in[0];
    const float* Alog = (const float*)d_in[1];
    const float* Dv   = (const float*)d_in[2];
    const float* Wx   = (const float*)d_in[3];
    const float* Wdt  = (const float*)d_in[4];
    const float* bdt  = (const float*)d_in[5];
    float* out = (float*)d_out;   // reference output dtype is float32

    float* ws   = (float*)d_ws;
    float* xdbl = ws;                                   // B*L*96     =   393216 f
    float* dtb  = xdbl + (size_t)BB * LL * 96;          // B*L*2048   =  8388608 f
    float* Ssum = dtb + (size_t)BB * LL * D_IN;         // B*C*2048   =   262144 f
    float* q    = Ssum + (size_t)BB * NCHUNK * D_IN;    // B*C*16*2048 = 4194304 f
    // total: 13,238,272 floats = 52.9 MB

    hipMemsetAsync(xdbl, 0, (size_t)BB * LL * 96 * sizeof(float), stream);
    gemm_xdbl <<<64 * G1_KSPLIT, 256, 0, stream>>>(u, Wx, xdbl);
    gemm_dt   <<<128 * 16,       256, 0, stream>>>(xdbl, Wdt, bdt, dtb);
    scan_pass1<<<BB * NCHUNK * 8, 256, 0, stream>>>(u, dtb, xdbl, Alog, Ssum, q);
    scan_combine<<<BB * 16 * D_IN / 256, 256, 0, stream>>>(Alog, Ssum, q);
    scan_pass2<<<BB * NCHUNK * 8, 256, 0, stream>>>(u, dtb, xdbl, Alog, Dv, q, out);
}

// Round 3
// 216.237 us; speedup vs baseline: 1.3814x; 1.3814x over previous
//
#include <hip/hip_runtime.h>
#include <hip/hip_bf16.h>

#define D_IN   2048
#define D_ST   16
#define DT_RK  64
#define BB     2
#define LL     2048
#define NCHUNK 64
#define LC     (LL / NCHUNK)   // 32
#define LOG2E  1.4426950408889634f

// ---------------------------------------------------------------------------
// Kernel 1: x_dbl[bl][k] = sum_d u[bl][d] * W_x[k][d]   (M=4096, N=96, K=2048)
// Split-K (8 ways) -> per-split partial buffers (NO atomics), then reduce.
// Block: 32 rows x 96 cols, K=256 per block. Grid = 128*8 = 1024 blocks (4/CU).
// ---------------------------------------------------------------------------
#define G1_MT 32
#define G1_KSPLIT 8
#define G1_KPER (D_IN / G1_KSPLIT)  // 256
#define G1_KC 64

__global__ __launch_bounds__(256) void gemm_xdbl(const float* __restrict__ u,
                                                 const float* __restrict__ Wx,
                                                 float* __restrict__ part) {
    __shared__ float us[G1_MT][G1_KC + 4];   // stride 68: consecutive rows 4 banks apart
    __shared__ float wxs[96][G1_KC + 4];
    const int mt  = blockIdx.x >> 3;         // 128 row tiles
    const int ks  = blockIdx.x & 7;
    const int row0 = mt * G1_MT;
    const int kb0  = ks * G1_KPER;
    const int tid = threadIdx.x;
    const int r0 = tid & 15;                 // rows r0 and r0+16 (consecutive across lanes)
    const int c0 = (tid >> 4) * 6;           // 6 cols

    float acc[2][6];
#pragma unroll
    for (int i = 0; i < 2; i++)
#pragma unroll
        for (int j = 0; j < 6; j++) acc[i][j] = 0.f;

    for (int kc = 0; kc < G1_KPER; kc += G1_KC) {
        const int kb = kb0 + kc;
        // stage u tile: 32 rows x 64 k  (512 float4, 2 per thread)
#pragma unroll
        for (int i = 0; i < 2; i++) {
            int f4 = tid + i * 256;
            int r = f4 >> 4, k4 = (f4 & 15) * 4;
            *(float4*)&us[r][k4] =
                *(const float4*)&u[(size_t)(row0 + r) * D_IN + kb + k4];
        }
        // stage Wx tile: 96 x 64  (1536 float4, 6 per thread)
#pragma unroll
        for (int i = 0; i < 6; i++) {
            int f4 = tid + i * 256;
            int c = f4 >> 4, k4 = (f4 & 15) * 4;
            *(float4*)&wxs[c][k4] =
                *(const float4*)&Wx[(size_t)c * D_IN + kb + k4];
        }
        __syncthreads();
#pragma unroll 4
        for (int k4 = 0; k4 < G1_KC; k4 += 4) {
            float4 av[2], bv[6];
            av[0] = *(const float4*)&us[r0][k4];
            av[1] = *(const float4*)&us[r0 + 16][k4];
#pragma unroll
            for (int j = 0; j < 6; j++) bv[j] = *(const float4*)&wxs[c0 + j][k4];
#pragma unroll
            for (int i = 0; i < 2; i++)
#pragma unroll
                for (int j = 0; j < 6; j++) {
                    acc[i][j] = fmaf(av[i].x, bv[j].x, acc[i][j]);
                    acc[i][j] = fmaf(av[i].y, bv[j].y, acc[i][j]);
                    acc[i][j] = fmaf(av[i].z, bv[j].z, acc[i][j]);
                    acc[i][j] = fmaf(av[i].w, bv[j].w, acc[i][j]);
                }
        }
        __syncthreads();
    }
    float* pp = part + (size_t)ks * (BB * LL * 96);
#pragma unroll
    for (int i = 0; i < 2; i++)
#pragma unroll
        for (int j = 0; j < 6; j++)
            pp[(size_t)(row0 + r0 + 16 * i) * 96 + c0 + j] = acc[i][j];
}

// Reduce the 8 split-K partials into xdbl. 393216 floats = 98304 float4.
__global__ __launch_bounds__(256) void reduce_xdbl(const float* __restrict__ part,
                                                   float* __restrict__ xdbl) {
    const size_t i4 = ((size_t)blockIdx.x * 256 + threadIdx.x) * 4;
    const size_t stride = (size_t)BB * LL * 96;
    float4 s = *(const float4*)&part[i4];
#pragma unroll
    for (int k = 1; k < G1_KSPLIT; k++) {
        float4 v = *(const float4*)&part[k * stride + i4];
        s.x += v.x; s.y += v.y; s.z += v.z; s.w += v.w;
    }
    *(float4*)&xdbl[i4] = s;
}

// ---------------------------------------------------------------------------
// Kernel 2: dt[bl][d] = softplus( sum_r xdbl[bl][r] * W_dt[d][r] + b_dt[d] )
// M=4096, N=2048, K=64. Block: 32 rows x 128 cols, K in full.
// ---------------------------------------------------------------------------
#define G2_MT 32
#define G2_NT 128

__global__ __launch_bounds__(256) void gemm_dt(const float* __restrict__ xdbl,
                                               const float* __restrict__ Wdt,
                                               const float* __restrict__ bdt,
                                               float* __restrict__ dt) {
    __shared__ float rs[G2_MT][DT_RK + 4];
    __shared__ float wds[G2_NT][DT_RK + 4];
    const int rt = blockIdx.x >> 4;    // 128 row tiles
    const int ct = blockIdx.x & 15;    // 16 col tiles
    const int row0 = rt * G2_MT, col0 = ct * G2_NT;
    const int tid = threadIdx.x;

#pragma unroll
    for (int i = 0; i < 2; i++) {
        int f4 = tid + i * 256;        // 0..511
        int r = f4 >> 4, k4 = (f4 & 15) * 4;
        *(float4*)&rs[r][k4] = *(const float4*)&xdbl[(size_t)(row0 + r) * 96 + k4];
    }
#pragma unroll
    for (int i = 0; i < 8; i++) {
        int f4 = tid + i * 256;        // 0..2047
        int c = f4 >> 4, k4 = (f4 & 15) * 4;
        *(float4*)&wds[c][k4] = *(const float4*)&Wdt[(size_t)(col0 + c) * DT_RK + k4];
    }
    __syncthreads();

    const int r0 = (tid & 7) * 4;      // 4 rows
    const int c0 = (tid >> 3) * 4;     // 4 cols
    float acc[4][4];
#pragma unroll
    for (int i = 0; i < 4; i++)
#pragma unroll
        for (int j = 0; j < 4; j++) acc[i][j] = 0.f;

#pragma unroll
    for (int k4 = 0; k4 < DT_RK; k4 += 4) {
        float4 av[4], bv[4];
#pragma unroll
        for (int i = 0; i < 4; i++) av[i] = *(const float4*)&rs[r0 + i][k4];
#pragma unroll
        for (int j = 0; j < 4; j++) bv[j] = *(const float4*)&wds[c0 + j][k4];
#pragma unroll
        for (int i = 0; i < 4; i++)
#pragma unroll
            for (int j = 0; j < 4; j++) {
                acc[i][j] = fmaf(av[i].x, bv[j].x, acc[i][j]);
                acc[i][j] = fmaf(av[i].y, bv[j].y, acc[i][j]);
                acc[i][j] = fmaf(av[i].z, bv[j].z, acc[i][j]);
                acc[i][j] = fmaf(av[i].w, bv[j].w, acc[i][j]);
            }
    }
#pragma unroll
    for (int j = 0; j < 4; j++) {
        float bj = bdt[col0 + c0 + j];
#pragma unroll
        for (int i = 0; i < 4; i++) {
            float x = acc[i][j] + bj;
            // softplus, overflow-safe
            float sp = fmaxf(x, 0.f) + log1pf(expf(-fabsf(x)));
            dt[(size_t)(row0 + r0 + i) * D_IN + col0 + c0 + j] = sp;
        }
    }
}

// ---------------------------------------------------------------------------
// Scan pass 1: per (b, chunk, d): local scan from h=0 over LC steps.
// Outputs: Ssum[b][c][d] = sum dt;  q[b][c][n][d] = local final state.
// ---------------------------------------------------------------------------
__global__ __launch_bounds__(256) void scan_pass1(const float* __restrict__ u,
                                                  const float* __restrict__ dt,
                                                  const float* __restrict__ xdbl,
                                                  const float* __restrict__ Alog,
                                                  float* __restrict__ Ssum,
                                                  float* __restrict__ q) {
    __shared__ float bc[LC][32];   // [t][0:16]=B_t, [t][16:32]=C_t
    const int blk = blockIdx.x;
    const int b  = blk >> 9;          // / (64 chunks * 8 dblocks)
    const int c  = (blk >> 3) & 63;
    const int db = blk & 7;
    const int tid = threadIdx.x;
    const int d = db * 256 + tid;
    const int t0 = c * LC;

    {   // stage B/C rows: LC*32 = 1024 floats = 256 float4
        int t = tid >> 3, j4 = (tid & 7) * 4;
        *(float4*)&bc[t][j4] =
            *(const float4*)&xdbl[(size_t)(b * LL + t0 + t) * 96 + 64 + j4];
    }
    float A2[16];
#pragma unroll
    for (int n4 = 0; n4 < 4; n4++) {
        float4 a = *(const float4*)&Alog[(size_t)d * 16 + n4 * 4];
        A2[n4 * 4 + 0] = -expf(a.x) * LOG2E;
        A2[n4 * 4 + 1] = -expf(a.y) * LOG2E;
        A2[n4 * 4 + 2] = -expf(a.z) * LOG2E;
        A2[n4 * 4 + 3] = -expf(a.w) * LOG2E;
    }
    __syncthreads();

    float h[16];
#pragma unroll
    for (int n = 0; n < 16; n++) h[n] = 0.f;
    float S = 0.f;

    const float* dtp = &dt[(size_t)(b * LL + t0) * D_IN + d];
    const float* up  = &u [(size_t)(b * LL + t0) * D_IN + d];
    float dt_nxt = dtp[0], u_nxt = up[0];
    for (int t = 0; t < LC; t++) {
        float dv = dt_nxt, uv = u_nxt;
        if (t + 1 < LC) { dt_nxt = dtp[(size_t)(t + 1) * D_IN]; u_nxt = up[(size_t)(t + 1) * D_IN]; }
        S += dv;
        float dtu = dv * uv;
        float4 b0 = *(const float4*)&bc[t][0];
        float4 b1 = *(const float4*)&bc[t][4];
        float4 b2 = *(const float4*)&bc[t][8];
        float4 b3 = *(const float4*)&bc[t][12];
        const float Bt[16] = {b0.x,b0.y,b0.z,b0.w, b1.x,b1.y,b1.z,b1.w,
                              b2.x,b2.y,b2.z,b2.w, b3.x,b3.y,b3.z,b3.w};
#pragma unroll
        for (int n = 0; n < 16; n++) {
            float a = __builtin_amdgcn_exp2f(dv * A2[n]);
            h[n] = fmaf(a, h[n], dtu * Bt[n]);
        }
    }
    Ssum[(size_t)(b * NCHUNK + c) * D_IN + d] = S;
#pragma unroll
    for (int n = 0; n < 16; n++)
        q[((size_t)((b * NCHUNK + c) * 16 + n)) * D_IN + d] = h[n];
}

// ---------------------------------------------------------------------------
// Combine: per (b,n,d): sequentially fold chunks IN-PLACE.
// On exit q[b][c][n][d] holds h_init for chunk c (the pre-chunk state).
// ---------------------------------------------------------------------------
__global__ __launch_bounds__(256) void scan_combine(const float* __restrict__ Alog,
                                                    const float* __restrict__ Ssum,
                                                    float* __restrict__ q) {
    const int gid = blockIdx.x * 256 + threadIdx.x;  // B*16*2048 = 65536
    const int d = gid & 2047;
    const int n = (gid >> 11) & 15;
    const int b = gid >> 15;
    const float A2 = -expf(Alog[(size_t)d * 16 + n]) * LOG2E;
    float h = 0.f;
    for (int c = 0; c < NCHUNK; c++) {
        size_t idx = ((size_t)((b * NCHUNK + c) * 16 + n)) * D_IN + d;
        float qv = q[idx];
        float S  = Ssum[(size_t)(b * NCHUNK + c) * D_IN + d];
        q[idx] = h;   // h_init for chunk c
        h = fmaf(__builtin_amdgcn_exp2f(A2 * S), h, qv);
    }
}

// ---------------------------------------------------------------------------
// Scan pass 2: re-scan each chunk from h_init, emit y = sum_n h*C + u*D (fp32)
// ---------------------------------------------------------------------------
__global__ __launch_bounds__(256) void scan_pass2(const float* __restrict__ u,
                                                  const float* __restrict__ dt,
                                                  const float* __restrict__ xdbl,
                                                  const float* __restrict__ Alog,
                                                  const float* __restrict__ Dv,
                                                  const float* __restrict__ hinit,
                                                  float* __restrict__ out) {
    __shared__ float bc[LC][32];
    const int blk = blockIdx.x;
    const int b  = blk >> 9;
    const int c  = (blk >> 3) & 63;
    const int db = blk & 7;
    const int tid = threadIdx.x;
    const int d = db * 256 + tid;
    const int t0 = c * LC;

    {
        int t = tid >> 3, j4 = (tid & 7) * 4;
        *(float4*)&bc[t][j4] =
            *(const float4*)&xdbl[(size_t)(b * LL + t0 + t) * 96 + 64 + j4];
    }
    float A2[16];
#pragma unroll
    for (int n4 = 0; n4 < 4; n4++) {
        float4 a = *(const float4*)&Alog[(size_t)d * 16 + n4 * 4];
        A2[n4 * 4 + 0] = -expf(a.x) * LOG2E;
        A2[n4 * 4 + 1] = -expf(a.y) * LOG2E;
        A2[n4 * 4 + 2] = -expf(a.z) * LOG2E;
        A2[n4 * 4 + 3] = -expf(a.w) * LOG2E;
    }
    const float Dd = Dv[d];
    float h[16];
#pragma unroll
    for (int n = 0; n < 16; n++)
        h[n] = hinit[((size_t)((b * NCHUNK + c) * 16 + n)) * D_IN + d];
    __syncthreads();

    const float* dtp = &dt[(size_t)(b * LL + t0) * D_IN + d];
    const float* up  = &u [(size_t)(b * LL + t0) * D_IN + d];
    float* op = &out[(size_t)(b * LL + t0) * D_IN + d];
    float dt_nxt = dtp[0], u_nxt = up[0];
    for (int t = 0; t < LC; t++) {
        float dv = dt_nxt, uv = u_nxt;
        if (t + 1 < LC) { dt_nxt = dtp[(size_t)(t + 1) * D_IN]; u_nxt = up[(size_t)(t + 1) * D_IN]; }
        float dtu = dv * uv;
        float4 b0 = *(const float4*)&bc[t][0];
        float4 b1 = *(const float4*)&bc[t][4];
        float4 b2 = *(const float4*)&bc[t][8];
        float4 b3 = *(const float4*)&bc[t][12];
        float4 c0v = *(const float4*)&bc[t][16];
        float4 c1v = *(const float4*)&bc[t][20];
        float4 c2v = *(const float4*)&bc[t][24];
        float4 c3v = *(const float4*)&bc[t][28];
        const float Bt[16] = {b0.x,b0.y,b0.z,b0.w, b1.x,b1.y,b1.z,b1.w,
                              b2.x,b2.y,b2.z,b2.w, b3.x,b3.y,b3.z,b3.w};
        const float Ct[16] = {c0v.x,c0v.y,c0v.z,c0v.w, c1v.x,c1v.y,c1v.z,c1v.w,
                              c2v.x,c2v.y,c2v.z,c2v.w, c3v.x,c3v.y,c3v.z,c3v.w};
        float y = 0.f;
#pragma unroll
        for (int n = 0; n < 16; n++) {
            float a = __builtin_amdgcn_exp2f(dv * A2[n]);
            h[n] = fmaf(a, h[n], dtu * Bt[n]);
            y = fmaf(h[n], Ct[n], y);
        }
        op[(size_t)t * D_IN] = fmaf(uv, Dd, y);
    }
}

// ---------------------------------------------------------------------------
extern "C" void kernel_launch(void* const* d_in, const int* in_sizes, int n_in,
                              void* d_out, int out_size, void* d_ws, size_t ws_size,
                              hipStream_t stream) {
    const float* u    = (const float*)d_in[0];
    const float* Alog = (const float*)d_in[1];
    const float* Dv   = (const float*)d_in[2];
    const float* Wx   = (const float*)d_in[3];
    const float* Wdt  = (const float*)d_in[4];
    const float* bdt  = (const float*)d_in[5];
    float* out = (float*)d_out;   // reference output dtype is float32

    float* ws   = (float*)d_ws;
    float* xdbl = ws;                                   // B*L*96     =   393216 f
    float* dtb  = xdbl + (size_t)BB * LL * 96;          // B*L*2048   =  8388608 f
    float* Ssum = dtb + (size_t)BB * LL * D_IN;         // B*C*2048   =   262144 f
    float* q    = Ssum + (size_t)BB * NCHUNK * D_IN;    // B*C*16*2048 = 4194304 f
    // split-K partials (8 * 393216 = 3145728 f) alias the Ssum+q region:
    // they are dead after reduce_xdbl, before Ssum/q are first written.
    float* part = Ssum;
    // total: 13,238,272 floats = 52.9 MB (same as previous passing round)

    gemm_xdbl <<<128 * G1_KSPLIT, 256, 0, stream>>>(u, Wx, part);
    reduce_xdbl<<<384,            256, 0, stream>>>(part, xdbl);
    gemm_dt   <<<128 * 16,        256, 0, stream>>>(xdbl, Wdt, bdt, dtb);
    scan_pass1<<<BB * NCHUNK * 8, 256, 0, stream>>>(u, dtb, xdbl, Alog, Ssum, q);
    scan_combine<<<BB * 16 * D_IN / 256, 256, 0, stream>>>(Alog, Ssum, q);
    scan_pass2<<<BB * NCHUNK * 8, 256, 0, stream>>>(u, dtb, xdbl, Alog, Dv, q, out);
}